// Round 20
// baseline (132.467 us; speedup 1.0000x reference)
//
#include <hip/hip_runtime.h>
#include <math.h>

typedef unsigned short u16;
typedef __attribute__((ext_vector_type(8))) short bf8;
typedef __attribute__((ext_vector_type(4))) short s4v;
typedef __attribute__((ext_vector_type(4))) float f4;
typedef __attribute__((ext_vector_type(16))) float f16v;

#define MFMA(a, b, c)   __builtin_amdgcn_mfma_f32_16x16x32_bf16(a, b, c, 0, 0, 0)
#define MFMA32(a, b, c) __builtin_amdgcn_mfma_f32_32x32x16_bf16(a, b, c, 0, 0, 0)

#if defined(__has_builtin)
#if __has_builtin(__builtin_amdgcn_exp2f)
#define EXP2(x) __builtin_amdgcn_exp2f(x)
#endif
#endif
#ifndef EXP2
#define EXP2(x) exp2f(x)
#endif

__device__ __forceinline__ u16 f2bf(float f) {
    unsigned u = __float_as_uint(f);
    u += 0x7fffu + ((u >> 16) & 1u);
    return (u16)(u >> 16);
}
__device__ __forceinline__ float bf2f(u16 h) {
    return __uint_as_float(((unsigned)h) << 16);
}
__device__ __forceinline__ void split2(float v, u16& h, u16& l) {
    h = f2bf(v);
    l = f2bf(v - bf2f(h));
}
// pack two fp32 (truncating) into one u32 of 2 bf16: low short = a, high = b
__device__ __forceinline__ unsigned pk2(float a, float b) {
    return (__float_as_uint(a) >> 16) | (__float_as_uint(b) & 0xffff0000u);
}
__device__ __forceinline__ void ldg_lds16(const u16* g, u16* l) {
    __builtin_amdgcn_global_load_lds(
        (const __attribute__((address_space(1))) unsigned int*)g,
        (__attribute__((address_space(3))) unsigned int*)l, 16, 0, 0);
}

// ---------------------------------------------------------------------------
// Fused GN pass 1 + weight prep. Blocks [0,1024): x partial sums.
// Blocks [1024,5120): cast qkv_w (786432) then proj_w (262144) to bf16.
// ---------------------------------------------------------------------------
__global__ __launch_bounds__(256) void gn_partial_prep(
    const float* __restrict__ x, float2* __restrict__ partial,
    const float* __restrict__ wq, const float* __restrict__ wp,
    u16* __restrict__ qwh, u16* __restrict__ pwh)
{
    const int tid = threadIdx.x;
    if (blockIdx.x >= 1024) {
        const int i = (blockIdx.x - 1024) * 256 + tid;
        if (i < 786432) qwh[i] = f2bf(wq[i]);
        else            pwh[i - 786432] = f2bf(wp[i - 786432]);
        return;
    }
    const int p = blockIdx.x;
    const float4* x4 = (const float4*)x + (size_t)p * 2048;
    float s = 0.f, ss = 0.f;
    for (int i = tid; i < 2048; i += 256) {
        float4 v = x4[i];
        s  += v.x + v.y + v.z + v.w;
        ss += v.x*v.x + v.y*v.y + v.z*v.z + v.w*v.w;
    }
    for (int off = 32; off > 0; off >>= 1) {
        s  += __shfl_down(s, off);
        ss += __shfl_down(ss, off);
    }
    __shared__ float red[8];
    const int wvi = tid >> 6;
    if ((tid & 63) == 0) { red[wvi] = s; red[4 + wvi] = ss; }
    __syncthreads();
    if (tid == 0)
        partial[p] = make_float2(red[0] + red[1] + red[2] + red[3],
                                 red[4] + red[5] + red[6] + red[7]);
}

// ---------------------------------------------------------------------------
// GN pass 2: reduce own group's 8 partials (redundant per block, trivial),
// then normalize + bf16 + transpose to xn_t[b][s][c].
// ---------------------------------------------------------------------------
__global__ __launch_bounds__(256) void gn_apply(
    const float* __restrict__ x, const float* __restrict__ gw,
    const float* __restrict__ gb, const float2* __restrict__ partial,
    u16* __restrict__ xh)
{
    const int blk = blockIdx.x;
    const int bg = blk >> 3, sc = (blk & 7) * 128;
    const int b = bg >> 3, g = bg & 7;
    const size_t base = (size_t)bg * 65536;
    float s = 0.f, ss = 0.f;
    #pragma unroll
    for (int i = 0; i < 8; ++i) {
        float2 pp = partial[bg*8 + i];
        s += pp.x; ss += pp.y;
    }
    const float mu = s * (1.f / 65536.f);
    const float rstd = rsqrtf(ss * (1.f / 65536.f) - mu * mu + 1e-5f);
    const int tid = threadIdx.x;

    __shared__ float tile[64][65];
    for (int s0 = sc; s0 < sc + 128; s0 += 64) {
        for (int idx = tid; idx < 1024; idx += 256) {
            const int c = idx >> 4, s4i = (idx & 15) * 4;
            const float w = gw[g*64 + c], bb = gb[g*64 + c];
            float4 v = *(const float4*)&x[base + (size_t)c*1024 + s0 + s4i];
            tile[s4i + 0][c] = (v.x - mu)*rstd*w + bb;
            tile[s4i + 1][c] = (v.y - mu)*rstd*w + bb;
            tile[s4i + 2][c] = (v.z - mu)*rstd*w + bb;
            tile[s4i + 3][c] = (v.w - mu)*rstd*w + bb;
        }
        __syncthreads();
        for (int idx = tid; idx < 1024; idx += 256) {
            const int srow = idx >> 4, c4 = (idx & 15) * 4;
            s4v hv;
            #pragma unroll
            for (int j = 0; j < 4; ++j)
                hv[j] = (short)f2bf(tile[srow][c4 + j]);
            const size_t o = ((size_t)b*1024 + s0 + srow)*512 + g*64 + c4;
            *(s4v*)&xh[o] = hv;
        }
        __syncthreads();
    }
}

// ---------------------------------------------------------------------------
// QKV GEMM: pure bf16, 1 MFMA (16x16x32). BM=BN=128, BK=64. LDS 32 KB.
// q (scaled 0.125*log2e), k: bf16 [bh][s][64]; v: bf16 [bh][64][s].
// ---------------------------------------------------------------------------
__global__ __launch_bounds__(256, 4) void qkv_mfma(
    const u16* __restrict__ Ah, const u16* __restrict__ Bh,
    const float* __restrict__ bias,
    u16* __restrict__ qh, u16* __restrict__ kh, u16* __restrict__ vh)
{
    __shared__ u16 smem[2*8192];          // [A:128x64][B:128x64]
    const int tid = threadIdx.x;
    const int wv = tid >> 6, ln = tid & 63;
    const int lr = ln & 15, lg = ln >> 4;
    const int m0 = blockIdx.x * 128;
    const int n0 = blockIdx.y * 128;
    const int b  = blockIdx.z;
    const size_t Abase = ((size_t)b*1024 + m0) * 512;
    const size_t Bbase = (size_t)n0 * 512;
    const int wm = (wv >> 1) * 64, wn = (wv & 1) * 64;
    const int srr = ln >> 3, sg = ln & 7;

    f4 acc[4][4] = {};

    for (int k0 = 0; k0 < 512; k0 += 64) {
        __syncthreads();
        #pragma unroll
        for (int it = 0; it < 8; ++it) {
            const int chunk = wv*8 + it;           // 32 x 1KB chunks
            const int plane = chunk >> 4;          // 0=A, 1=B
            const int row = ((chunk & 15) << 3) + srr;
            const u16* srcp = (plane == 0) ? (Ah + Abase) : (Bh + Bbase);
            const u16* gp = srcp + (size_t)row*512 + k0 + ((sg ^ (row & 7)) << 3);
            ldg_lds16(gp, smem + chunk*512);
        }
        __syncthreads();
        #pragma unroll
        for (int f = 0; f < 2; ++f) {
            bf8 av[4], b0[4];
            #pragma unroll
            for (int mf = 0; mf < 4; ++mf) {
                const int row = wm + mf*16 + lr;
                const int ch = (f*4 + lg) ^ (row & 7);
                av[mf] = *(const bf8*)&smem[row*64 + (ch << 3)];
            }
            #pragma unroll
            for (int nf = 0; nf < 4; ++nf) {
                const int row = wn + nf*16 + lr;
                const int ch = (f*4 + lg) ^ (row & 7);
                b0[nf] = *(const bf8*)&smem[8192 + row*64 + (ch << 3)];
            }
            #pragma unroll
            for (int mf = 0; mf < 4; ++mf)
                #pragma unroll
                for (int nf = 0; nf < 4; ++nf)
                    acc[mf][nf] = MFMA(av[mf], b0[nf], acc[mf][nf]);
        }
    }

    #pragma unroll
    for (int nf = 0; nf < 4; ++nf) {
        const int o = n0 + wn + nf*16 + lr;
        const int which = o >> 9;
        const int hd = (o >> 6) & 7;
        const int dd = o & 63;
        const float bs = bias[o];
        const int bh = b*8 + hd;
        #pragma unroll
        for (int mf = 0; mf < 4; ++mf) {
            const int s = m0 + wm + mf*16 + lg*4;
            if (which == 2) {
                s4v hv;
                #pragma unroll
                for (int r = 0; r < 4; ++r)
                    hv[r] = (short)f2bf(acc[mf][nf][r] + bs);
                const size_t a = ((size_t)bh*64 + dd)*1024 + s;
                *(s4v*)&vh[a] = hv;
            } else {
                // q scaled by 1/sqrt(64)*log2(e): softmax in exp2 domain
                const float sc = (which == 0) ? 0.18033688011112042f : 1.f;
                u16* dst = (which == 0) ? qh : kh;
                const size_t a = ((size_t)bh*1024 + s)*64 + dd;
                #pragma unroll
                for (int r = 0; r < 4; ++r)
                    dst[a + (size_t)r*64] = f2bf((acc[mf][nf][r] + bs)*sc);
            }
        }
    }
}

// ---------------------------------------------------------------------------
// Flash attention on 32x32x16 MFMAs. Wave owns 32 q-rows (i = lane&31).
// S^T = K*Q: lane holds P[i=lane&31][16 j] in regs; softmax lane-local.
// PV uses a PERMUTED slot->j bijection so the A-fragment is the lane's OWN
// p registers packed in order (no shfl, no cndmask): slot k=8L+jj holds
// j=(jj&3)+8*(jj>>2)+4L; the V B-fragment reads the matching rows as two
// ds_read_b64 per (h,dn). MFMA contraction is slot-order-agnostic, so this
// is numerically identical to the natural order.
// Layouts (HW-verified m74/m101): D row=(r&3)+8*(r>>2)+4*(lane>>5),
// col=lane&31; A/B row|col=lane&31, k=(lane>>5)*8+jj.
// K,V double-buffered LDS; explicit vmcnt(0) drain before each barrier.
// LDS ~33 KB -> 4 blocks/CU.
// ---------------------------------------------------------------------------
__global__ __launch_bounds__(256, 4) void attn_mfma(
    const u16* __restrict__ qh_, const u16* __restrict__ kh_,
    const u16* __restrict__ vh_,
    u16* __restrict__ oh_, u16* __restrict__ ol_)
{
    __shared__ u16 Kt[2][64][64];
    __shared__ u16 Vt[2][64][64];
    __shared__ float lsh[4][32];
    const int tid = threadIdx.x;
    const int wv = tid >> 6, ln = tid & 63;
    const int l31 = ln & 31, L = ln >> 5;
    // XCD-aware swizzle: all 8 q-tiles of one bh on one XCD, consecutive.
    const int flat = blockIdx.x + (blockIdx.y << 3);
    const int bh = ((flat & 7) << 4) + (flat >> 6);
    const int q0 = ((flat >> 3) & 7) * 128;
    const size_t qkb = (size_t)bh * 65536;
    const int srr = ln >> 3, sg = ln & 7;

    // Q fragments: B-operand, col i = l31, k = L*8.. per 16-k block dk
    bf8 qf[4];
    #pragma unroll
    for (int dk = 0; dk < 4; ++dk)
        qf[dk] = *(const bf8*)&qh_[qkb
            + (size_t)(q0 + wv*32 + l31)*64 + dk*16 + L*8];

    float lpart = 0.f;
    f16v oacc[2] = {};

    // prologue: stage tile 0 into buf 0 (16 x 1KB chunks: K 0-7, V 8-15)
    #pragma unroll
    for (int it = 0; it < 4; ++it) {
        const int chunk = wv*4 + it;
        const int row = (chunk & 7)*8 + srr;
        const u16* gp = (chunk < 8)
            ? kh_ + qkb + (size_t)row*64 + ((sg ^ (row & 7)) << 3)
            : vh_ + qkb + (size_t)row*1024 + ((sg ^ (row & 7)) << 3);
        u16* dst = ((chunk < 8) ? &Kt[0][0][0] : &Vt[0][0][0]) + (chunk & 7)*512;
        ldg_lds16(gp, dst);
    }

    for (int t = 0; t < 16; ++t) {
        const int cur = t & 1;
        const int j0 = t * 64;
        const u16* kbuf = &Kt[cur][0][0];
        const u16* vbuf = &Vt[cur][0][0];

        asm volatile("s_waitcnt vmcnt(0)" ::: "memory");
        __syncthreads();

        if (t < 15) {
            #pragma unroll
            for (int it = 0; it < 4; ++it) {
                const int chunk = wv*4 + it;
                const int row = (chunk & 7)*8 + srr;
                const u16* gp = (chunk < 8)
                    ? kh_ + qkb + (size_t)(j0 + 64 + row)*64
                          + ((sg ^ (row & 7)) << 3)
                    : vh_ + qkb + (size_t)row*1024 + j0 + 64
                          + ((sg ^ (row & 7)) << 3);
                u16* dst = ((chunk < 8) ? &Kt[cur^1][0][0] : &Vt[cur^1][0][0])
                           + (chunk & 7)*512;
                ldg_lds16(gp, dst);
            }
        }

        #pragma unroll
        for (int jb = 0; jb < 2; ++jb) {
            // S^T block: rows j = jb*32 + [0,32), cols i (lane-local)
            f16v sacc = {};
            #pragma unroll
            for (int dk = 0; dk < 4; ++dk) {
                const int row = jb*32 + l31;
                const int ch = (dk*2 + L) ^ (row & 7);
                const bf8 kv = *(const bf8*)&kbuf[row*64 + (ch << 3)];
                sacc = MFMA32(kv, qf[dk], sacc);
            }
            // softmax (exp2-domain, no max tracking: scores bounded)
            float p[16];
            float ps = 0.f;
            #pragma unroll
            for (int r = 0; r < 16; ++r) { p[r] = EXP2(sacc[r]); ps += p[r]; }
            lpart += ps;

            // PV: A = own p regs in order; B = V rows via permuted bijection
            #pragma unroll
            for (int h = 0; h < 2; ++h) {
                unsigned pu[4];
                pu[0] = pk2(p[h*8+0], p[h*8+1]);
                pu[1] = pk2(p[h*8+2], p[h*8+3]);
                pu[2] = pk2(p[h*8+4], p[h*8+5]);
                pu[3] = pk2(p[h*8+6], p[h*8+7]);
                const bf8 pa = *(const bf8*)pu;
                const int blk2 = (jb*2 + h)*2;     // global 8-col chunk pair
                #pragma unroll
                for (int dn = 0; dn < 2; ++dn) {
                    const int d = dn*32 + l31;
                    const int ca = ((blk2 ^ (d & 7)) << 3) + 4*L;
                    const int cb = (((blk2 + 1) ^ (d & 7)) << 3) + 4*L;
                    const s4v va = *(const s4v*)&vbuf[d*64 + ca];
                    const s4v vb = *(const s4v*)&vbuf[d*64 + cb];
                    bf8 vvf;
                    vvf[0] = va[0]; vvf[1] = va[1];
                    vvf[2] = va[2]; vvf[3] = va[3];
                    vvf[4] = vb[0]; vvf[5] = vb[1];
                    vvf[6] = vb[2]; vvf[7] = vb[3];
                    oacc[dn] = MFMA32(pa, vvf, oacc[dn]);
                }
            }
        }
    }

    // row sums: lane + lane^32 hold complementary j for the same i
    lpart += __shfl_xor(lpart, 32);
    if (L == 0) lsh[wv][l31] = lpart;

    const int b = bh >> 3, h = bh & 7;
    #pragma unroll
    for (int dn = 0; dn < 2; ++dn) {
        #pragma unroll
        for (int r = 0; r < 16; ++r) {
            const int irow = (r & 3) + 8*(r >> 2) + 4*L;
            const float inv = 1.f / lsh[wv][irow];
            const float val = oacc[dn][r] * inv;
            const int s = q0 + wv*32 + irow;
            const int dd = dn*32 + l31;
            const size_t a = ((size_t)b*1024 + s)*512 + h*64 + dd;
            u16 hh, ll; split2(val, hh, ll);
            oh_[a] = hh;
            ol_[a] = ll;
        }
    }
}

// ---------------------------------------------------------------------------
// Proj GEMM + bias + residual. Pure bf16 GEMM (O_hi x W_hi, 1 MFMA);
// residual uses full O (hi+lo). LDS 32 KB.
// ---------------------------------------------------------------------------
__global__ __launch_bounds__(256, 4) void proj_mfma(
    const u16* __restrict__ Ah, const u16* __restrict__ Al,
    const u16* __restrict__ Bh,
    const float* __restrict__ bias, float* __restrict__ out)
{
    __shared__ u16 smem[2*8192];          // [A:128x64][B:128x64]
    const int tid = threadIdx.x;
    const int wv = tid >> 6, ln = tid & 63;
    const int lr = ln & 15, lg = ln >> 4;
    const int m0 = blockIdx.x * 128;
    const int n0 = blockIdx.y * 128;
    const int b  = blockIdx.z;
    const size_t Abase = ((size_t)b*1024 + m0) * 512;
    const size_t Bbase = (size_t)n0 * 512;
    const int wm = (wv >> 1) * 64, wn = (wv & 1) * 64;
    const int srr = ln >> 3, sg = ln & 7;

    f4 acc[4][4] = {};

    for (int k0 = 0; k0 < 512; k0 += 64) {
        __syncthreads();
        #pragma unroll
        for (int it = 0; it < 8; ++it) {
            const int chunk = wv*8 + it;
            const int plane = chunk >> 4;          // 0=A, 1=B
            const int row = ((chunk & 15) << 3) + srr;
            const u16* srcp = (plane == 0) ? (Ah + Abase) : (Bh + Bbase);
            const u16* gp = srcp + (size_t)row*512 + k0 + ((sg ^ (row & 7)) << 3);
            ldg_lds16(gp, smem + chunk*512);
        }
        __syncthreads();
        #pragma unroll
        for (int f = 0; f < 2; ++f) {
            bf8 av[4], b0[4];
            #pragma unroll
            for (int mf = 0; mf < 4; ++mf) {
                const int row = wm + mf*16 + lr;
                const int ch = (f*4 + lg) ^ (row & 7);
                av[mf] = *(const bf8*)&smem[row*64 + (ch << 3)];
            }
            #pragma unroll
            for (int nf = 0; nf < 4; ++nf) {
                const int row = wn + nf*16 + lr;
                const int ch = (f*4 + lg) ^ (row & 7);
                b0[nf] = *(const bf8*)&smem[8192 + row*64 + (ch << 3)];
            }
            #pragma unroll
            for (int mf = 0; mf < 4; ++mf)
                #pragma unroll
                for (int nf = 0; nf < 4; ++nf)
                    acc[mf][nf] = MFMA(av[mf], b0[nf], acc[mf][nf]);
        }
    }

    #pragma unroll
    for (int nf = 0; nf < 4; ++nf) {
        const int o = n0 + wn + nf*16 + lr;
        const float bs = bias[o];
        #pragma unroll
        for (int mf = 0; mf < 4; ++mf) {
            const int s = m0 + wm + mf*16 + lg*4;
            const size_t ob = ((size_t)b*1024 + s)*512 + o;
            float4 r;
            r.x = acc[mf][nf][0] + bs + bf2f(Ah[ob])         + bf2f(Al[ob]);
            r.y = acc[mf][nf][1] + bs + bf2f(Ah[ob + 512])   + bf2f(Al[ob + 512]);
            r.z = acc[mf][nf][2] + bs + bf2f(Ah[ob + 1024])  + bf2f(Al[ob + 1024]);
            r.w = acc[mf][nf][3] + bs + bf2f(Ah[ob + 1536])  + bf2f(Al[ob + 1536]);
            *(float4*)&out[((size_t)b*512 + o)*1024 + s] = r;
        }
    }
}

extern "C" void kernel_launch(void* const* d_in, const int* in_sizes, int n_in,
                              void* d_out, int out_size, void* d_ws, size_t ws_size,
                              hipStream_t stream) {
    const float* x      = (const float*)d_in[0];
    const float* gn_w   = (const float*)d_in[1];
    const float* gn_b   = (const float*)d_in[2];
    const float* qkv_w  = (const float*)d_in[3];
    const float* qkv_b  = (const float*)d_in[4];
    const float* proj_w = (const float*)d_in[5];
    const float* proj_b = (const float*)d_in[6];
    float* out = (float*)d_out;

    u16* w = (u16*)d_ws;
    const size_t P = 8388608UL;           // B*C*S elements
    u16* xh = w;                                   // plane 0: xn_t hi; later oh
    u16* ol = w + P;                               // plane 1: attn lo output
    u16* qh = w + 2*P;                             // plane 2: q bf16
    u16* pwh = w + 3*P;                            // plane 3: proj_w bf16
    u16* kh = w + 4*P;                             // plane 4: k bf16
    u16* vh = w + 6*P;                             // plane 6: v bf16
    u16* oh = xh;
    // qkv_w cast -> d_out scratch (qkv_mfma only READS d_out; safe).
    u16* qwh = (u16*)d_out;
    // GN partials in plane 5 (always free)
    float2* partial = (float2*)(w + 5*P);          // 1024 float2

    hipLaunchKernelGGL(gn_partial_prep, dim3(5120), dim3(256), 0, stream,
                       x, partial, qkv_w, proj_w, qwh, pwh);
    hipLaunchKernelGGL(gn_apply, dim3(1024), dim3(256), 0, stream,
                       x, gn_w, gn_b, partial, xh);
    hipLaunchKernelGGL(qkv_mfma, dim3(8, 12, 16), dim3(256), 0, stream,
                       xh, qwh, qkv_b, qh, kh, vh);
    hipLaunchKernelGGL(attn_mfma, dim3(8, 128), dim3(256), 0, stream,
                       qh, kh, vh, oh, ol);
    hipLaunchKernelGGL(proj_mfma, dim3(8, 4, 16), dim3(256), 0, stream,
                       oh, ol, pwh, proj_b, out);
}

// Round 21
// 128.251 us; speedup vs baseline: 1.0329x; 1.0329x over previous
//
#include <hip/hip_runtime.h>
#include <math.h>

typedef unsigned short u16;
typedef __attribute__((ext_vector_type(8))) short bf8;
typedef __attribute__((ext_vector_type(4))) short s4v;
typedef __attribute__((ext_vector_type(4))) float f4;

#define MFMA(a, b, c) __builtin_amdgcn_mfma_f32_16x16x32_bf16(a, b, c, 0, 0, 0)

#if defined(__has_builtin)
#if __has_builtin(__builtin_amdgcn_exp2f)
#define EXP2(x) __builtin_amdgcn_exp2f(x)
#endif
#endif
#ifndef EXP2
#define EXP2(x) exp2f(x)
#endif

__device__ __forceinline__ u16 f2bf(float f) {
    unsigned u = __float_as_uint(f);
    u += 0x7fffu + ((u >> 16) & 1u);
    return (u16)(u >> 16);
}
__device__ __forceinline__ float bf2f(u16 h) {
    return __uint_as_float(((unsigned)h) << 16);
}
__device__ __forceinline__ void split2(float v, u16& h, u16& l) {
    h = f2bf(v);
    l = f2bf(v - bf2f(h));
}
__device__ __forceinline__ void ldg_lds16(const u16* g, u16* l) {
    __builtin_amdgcn_global_load_lds(
        (const __attribute__((address_space(1))) unsigned int*)g,
        (__attribute__((address_space(3))) unsigned int*)l, 16, 0, 0);
}

// ---------------------------------------------------------------------------
// Fused GN pass 1 + weight prep. Blocks [0,1024): x partial sums.
// Blocks [1024,5120): cast qkv_w (786432) then proj_w (262144) to bf16.
// ---------------------------------------------------------------------------
__global__ __launch_bounds__(256) void gn_partial_prep(
    const float* __restrict__ x, float2* __restrict__ partial,
    const float* __restrict__ wq, const float* __restrict__ wp,
    u16* __restrict__ qwh, u16* __restrict__ pwh)
{
    const int tid = threadIdx.x;
    if (blockIdx.x >= 1024) {
        const int i = (blockIdx.x - 1024) * 256 + tid;
        if (i < 786432) qwh[i] = f2bf(wq[i]);
        else            pwh[i - 786432] = f2bf(wp[i - 786432]);
        return;
    }
    const int p = blockIdx.x;
    const float4* x4 = (const float4*)x + (size_t)p * 2048;
    float s = 0.f, ss = 0.f;
    for (int i = tid; i < 2048; i += 256) {
        float4 v = x4[i];
        s  += v.x + v.y + v.z + v.w;
        ss += v.x*v.x + v.y*v.y + v.z*v.z + v.w*v.w;
    }
    for (int off = 32; off > 0; off >>= 1) {
        s  += __shfl_down(s, off);
        ss += __shfl_down(ss, off);
    }
    __shared__ float red[8];
    const int wvi = tid >> 6;
    if ((tid & 63) == 0) { red[wvi] = s; red[4 + wvi] = ss; }
    __syncthreads();
    if (tid == 0)
        partial[p] = make_float2(red[0] + red[1] + red[2] + red[3],
                                 red[4] + red[5] + red[6] + red[7]);
}

// ---------------------------------------------------------------------------
// GN pass 2: reduce own group's 8 partials (redundant per block, trivial),
// then normalize + bf16 + transpose to xn_t[b][s][c].
// ---------------------------------------------------------------------------
__global__ __launch_bounds__(256) void gn_apply(
    const float* __restrict__ x, const float* __restrict__ gw,
    const float* __restrict__ gb, const float2* __restrict__ partial,
    u16* __restrict__ xh)
{
    const int blk = blockIdx.x;
    const int bg = blk >> 3, sc = (blk & 7) * 128;
    const int b = bg >> 3, g = bg & 7;
    const size_t base = (size_t)bg * 65536;
    float s = 0.f, ss = 0.f;
    #pragma unroll
    for (int i = 0; i < 8; ++i) {
        float2 pp = partial[bg*8 + i];
        s += pp.x; ss += pp.y;
    }
    const float mu = s * (1.f / 65536.f);
    const float rstd = rsqrtf(ss * (1.f / 65536.f) - mu * mu + 1e-5f);
    const int tid = threadIdx.x;

    __shared__ float tile[64][65];
    for (int s0 = sc; s0 < sc + 128; s0 += 64) {
        for (int idx = tid; idx < 1024; idx += 256) {
            const int c = idx >> 4, s4i = (idx & 15) * 4;
            const float w = gw[g*64 + c], bb = gb[g*64 + c];
            float4 v = *(const float4*)&x[base + (size_t)c*1024 + s0 + s4i];
            tile[s4i + 0][c] = (v.x - mu)*rstd*w + bb;
            tile[s4i + 1][c] = (v.y - mu)*rstd*w + bb;
            tile[s4i + 2][c] = (v.z - mu)*rstd*w + bb;
            tile[s4i + 3][c] = (v.w - mu)*rstd*w + bb;
        }
        __syncthreads();
        for (int idx = tid; idx < 1024; idx += 256) {
            const int srow = idx >> 4, c4 = (idx & 15) * 4;
            s4v hv;
            #pragma unroll
            for (int j = 0; j < 4; ++j)
                hv[j] = (short)f2bf(tile[srow][c4 + j]);
            const size_t o = ((size_t)b*1024 + s0 + srow)*512 + g*64 + c4;
            *(s4v*)&xh[o] = hv;
        }
        __syncthreads();
    }
}

// ---------------------------------------------------------------------------
// QKV GEMM: pure bf16, 1 MFMA (16x16x32). BM=BN=128, BK=64. LDS 32 KB.
// q (scaled 0.125*log2e), k: bf16 [bh][s][64]; v: bf16 [bh][64][s].
// ---------------------------------------------------------------------------
__global__ __launch_bounds__(256, 4) void qkv_mfma(
    const u16* __restrict__ Ah, const u16* __restrict__ Bh,
    const float* __restrict__ bias,
    u16* __restrict__ qh, u16* __restrict__ kh, u16* __restrict__ vh)
{
    __shared__ u16 smem[2*8192];          // [A:128x64][B:128x64]
    const int tid = threadIdx.x;
    const int wv = tid >> 6, ln = tid & 63;
    const int lr = ln & 15, lg = ln >> 4;
    const int m0 = blockIdx.x * 128;
    const int n0 = blockIdx.y * 128;
    const int b  = blockIdx.z;
    const size_t Abase = ((size_t)b*1024 + m0) * 512;
    const size_t Bbase = (size_t)n0 * 512;
    const int wm = (wv >> 1) * 64, wn = (wv & 1) * 64;
    const int srr = ln >> 3, sg = ln & 7;

    f4 acc[4][4] = {};

    for (int k0 = 0; k0 < 512; k0 += 64) {
        __syncthreads();
        #pragma unroll
        for (int it = 0; it < 8; ++it) {
            const int chunk = wv*8 + it;           // 32 x 1KB chunks
            const int plane = chunk >> 4;          // 0=A, 1=B
            const int row = ((chunk & 15) << 3) + srr;
            const u16* srcp = (plane == 0) ? (Ah + Abase) : (Bh + Bbase);
            const u16* gp = srcp + (size_t)row*512 + k0 + ((sg ^ (row & 7)) << 3);
            ldg_lds16(gp, smem + chunk*512);
        }
        __syncthreads();
        #pragma unroll
        for (int f = 0; f < 2; ++f) {
            bf8 av[4], b0[4];
            #pragma unroll
            for (int mf = 0; mf < 4; ++mf) {
                const int row = wm + mf*16 + lr;
                const int ch = (f*4 + lg) ^ (row & 7);
                av[mf] = *(const bf8*)&smem[row*64 + (ch << 3)];
            }
            #pragma unroll
            for (int nf = 0; nf < 4; ++nf) {
                const int row = wn + nf*16 + lr;
                const int ch = (f*4 + lg) ^ (row & 7);
                b0[nf] = *(const bf8*)&smem[8192 + row*64 + (ch << 3)];
            }
            #pragma unroll
            for (int mf = 0; mf < 4; ++mf)
                #pragma unroll
                for (int nf = 0; nf < 4; ++nf)
                    acc[mf][nf] = MFMA(av[mf], b0[nf], acc[mf][nf]);
        }
    }

    #pragma unroll
    for (int nf = 0; nf < 4; ++nf) {
        const int o = n0 + wn + nf*16 + lr;
        const int which = o >> 9;
        const int hd = (o >> 6) & 7;
        const int dd = o & 63;
        const float bs = bias[o];
        const int bh = b*8 + hd;
        #pragma unroll
        for (int mf = 0; mf < 4; ++mf) {
            const int s = m0 + wm + mf*16 + lg*4;
            if (which == 2) {
                s4v hv;
                #pragma unroll
                for (int r = 0; r < 4; ++r)
                    hv[r] = (short)f2bf(acc[mf][nf][r] + bs);
                const size_t a = ((size_t)bh*64 + dd)*1024 + s;
                *(s4v*)&vh[a] = hv;
            } else {
                // q scaled by 1/sqrt(64)*log2(e): softmax in exp2 domain
                const float sc = (which == 0) ? 0.18033688011112042f : 1.f;
                u16* dst = (which == 0) ? qh : kh;
                const size_t a = ((size_t)bh*1024 + s)*64 + dd;
                #pragma unroll
                for (int r = 0; r < 4; ++r)
                    dst[a + (size_t)r*64] = f2bf((acc[mf][nf][r] + bs)*sc);
            }
        }
    }
}

// ---------------------------------------------------------------------------
// Flash attention, 2-phase pipelined (measured-best round-14 version).
// QBLK=128 (wave owns 32 q-rows), KBLK=64. K and V double-buffered in LDS
// via global_load_lds; per tile: explicit vmcnt(0) drain + one barrier ->
// issue next-tile staging (in flight across compute) -> compute from LDS.
// S = K*Q (16x16x32, 1 MFMA); no max tracking (scores bounded); PV = P*V.
// Pt is PER-ii so the unrolled ii=0/ii=1 chains interleave. No setprio
// (measured -10% on this 2-phase structure). LDS 50 KB -> 3 blocks/CU.
// ---------------------------------------------------------------------------
__global__ __launch_bounds__(256, 3) void attn_mfma(
    const u16* __restrict__ qh_, const u16* __restrict__ kh_,
    const u16* __restrict__ vh_,
    u16* __restrict__ oh_, u16* __restrict__ ol_)
{
    __shared__ u16 Kt[2][64][64];
    __shared__ u16 Vt[2][64][64];
    __shared__ u16 Pt[4][2][16][72];      // [wave][ii][i][j(+pad)]
    const int tid = threadIdx.x;
    const int wv = tid >> 6, ln = tid & 63;
    const int lr = ln & 15, lg = ln >> 4;
    // XCD-aware swizzle: all 8 q-tiles of one bh on one XCD, consecutive.
    const int flat = blockIdx.x + (blockIdx.y << 3);
    const int bh = ((flat & 7) << 4) + (flat >> 6);
    const int q0 = ((flat >> 3) & 7) * 128;
    const size_t qkb = (size_t)bh * 65536;
    const int srr = ln >> 3, sg = ln & 7;

    bf8 qf[2][2];                         // [ii][f]
    #pragma unroll
    for (int ii = 0; ii < 2; ++ii)
        #pragma unroll
        for (int f = 0; f < 2; ++f)
            qf[ii][f] = *(const bf8*)&qh_[qkb
                + (size_t)(q0 + wv*32 + ii*16 + lr)*64 + f*32 + lg*8];

    float lpart[2] = {0.f, 0.f};
    f4 oacc[2][4] = {};

    // prologue: stage tile 0 into buf 0 (16 x 1KB chunks: K 0-7, V 8-15)
    #pragma unroll
    for (int it = 0; it < 4; ++it) {
        const int chunk = wv*4 + it;
        const int row = (chunk & 7)*8 + srr;
        const u16* gp = (chunk < 8)
            ? kh_ + qkb + (size_t)row*64 + ((sg ^ (row & 7)) << 3)
            : vh_ + qkb + (size_t)row*1024 + ((sg ^ (row & 7)) << 3);
        u16* dst = ((chunk < 8) ? &Kt[0][0][0] : &Vt[0][0][0]) + (chunk & 7)*512;
        ldg_lds16(gp, dst);
    }

    for (int t = 0; t < 16; ++t) {
        const int cur = t & 1;
        const int j0 = t * 64;
        const u16* kbuf = &Kt[cur][0][0];
        const u16* vbuf = &Vt[cur][0][0];

        // Explicit drain of this wave's outstanding global_load_lds, then
        // barrier: guarantees tile t is fully in LDS for every wave.
        asm volatile("s_waitcnt vmcnt(0)" ::: "memory");
        __syncthreads();

        // prefetch tile t+1 into the other buffer (in flight across compute)
        if (t < 15) {
            #pragma unroll
            for (int it = 0; it < 4; ++it) {
                const int chunk = wv*4 + it;
                const int row = (chunk & 7)*8 + srr;
                const u16* gp = (chunk < 8)
                    ? kh_ + qkb + (size_t)(j0 + 64 + row)*64
                          + ((sg ^ (row & 7)) << 3)
                    : vh_ + qkb + (size_t)row*1024 + j0 + 64
                          + ((sg ^ (row & 7)) << 3);
                u16* dst = ((chunk < 8) ? &Kt[cur^1][0][0] : &Vt[cur^1][0][0])
                           + (chunk & 7)*512;
                ldg_lds16(gp, dst);
            }
        }

        #pragma unroll
        for (int ii = 0; ii < 2; ++ii) {
            f4 sacc[4] = {};
            #pragma unroll
            for (int jf = 0; jf < 4; ++jf)
                #pragma unroll
                for (int f = 0; f < 2; ++f) {
                    const int row = jf*16 + lr;
                    const int ch = (f*4 + lg) ^ (row & 7);
                    const bf8 kv = *(const bf8*)&kbuf[row*64 + (ch << 3)];
                    sacc[jf] = MFMA(kv, qf[ii][f], sacc[jf]);
                }

            float ps = 0.f;
            #pragma unroll
            for (int jf = 0; jf < 4; ++jf) {
                s4v hv;
                #pragma unroll
                for (int r = 0; r < 4; ++r) {
                    const float p = EXP2(sacc[jf][r]);
                    ps += p;
                    hv[r] = (short)(__float_as_uint(p) >> 16);
                }
                *(s4v*)&Pt[wv][ii][lr][(jf*4 + lg)*4] = hv;
            }
            lpart[ii] += ps;

            #pragma unroll
            for (int f = 0; f < 2; ++f) {
                const bf8 pa = *(const bf8*)&Pt[wv][ii][lr][(f*4 + lg)*8];
                #pragma unroll
                for (int nf = 0; nf < 4; ++nf) {
                    const int row = nf*16 + lr;
                    const int ch = (f*4 + lg) ^ (row & 7);
                    const bf8 vv = *(const bf8*)&vbuf[row*64 + (ch << 3)];
                    oacc[ii][nf] = MFMA(pa, vv, oacc[ii][nf]);
                }
            }
        }
    }

    #pragma unroll
    for (int ii = 0; ii < 2; ++ii) {
        lpart[ii] += __shfl_xor(lpart[ii], 16);
        lpart[ii] += __shfl_xor(lpart[ii], 32);
    }

    const int b = bh >> 3, h = bh & 7;
    #pragma unroll
    for (int ii = 0; ii < 2; ++ii) {
        float inv[4];
        #pragma unroll
        for (int r = 0; r < 4; ++r)
            inv[r] = 1.f / __shfl(lpart[ii], lg*4 + r);
        #pragma unroll
        for (int nf = 0; nf < 4; ++nf) {
            const int dd = nf*16 + lr;
            #pragma unroll
            for (int r = 0; r < 4; ++r) {
                const int s = q0 + wv*32 + ii*16 + lg*4 + r;
                const float val = oacc[ii][nf][r] * inv[r];
                const size_t a = ((size_t)b*1024 + s)*512 + h*64 + dd;
                u16 hh, ll; split2(val, hh, ll);
                oh_[a] = hh;
                ol_[a] = ll;
            }
        }
    }
}

// ---------------------------------------------------------------------------
// Proj GEMM + bias + residual. Pure bf16 GEMM (O_hi x W_hi, 1 MFMA);
// residual uses full O (hi+lo). LDS 32 KB.
// ---------------------------------------------------------------------------
__global__ __launch_bounds__(256, 4) void proj_mfma(
    const u16* __restrict__ Ah, const u16* __restrict__ Al,
    const u16* __restrict__ Bh,
    const float* __restrict__ bias, float* __restrict__ out)
{
    __shared__ u16 smem[2*8192];          // [A:128x64][B:128x64]
    const int tid = threadIdx.x;
    const int wv = tid >> 6, ln = tid & 63;
    const int lr = ln & 15, lg = ln >> 4;
    const int m0 = blockIdx.x * 128;
    const int n0 = blockIdx.y * 128;
    const int b  = blockIdx.z;
    const size_t Abase = ((size_t)b*1024 + m0) * 512;
    const size_t Bbase = (size_t)n0 * 512;
    const int wm = (wv >> 1) * 64, wn = (wv & 1) * 64;
    const int srr = ln >> 3, sg = ln & 7;

    f4 acc[4][4] = {};

    for (int k0 = 0; k0 < 512; k0 += 64) {
        __syncthreads();
        #pragma unroll
        for (int it = 0; it < 8; ++it) {
            const int chunk = wv*8 + it;
            const int plane = chunk >> 4;          // 0=A, 1=B
            const int row = ((chunk & 15) << 3) + srr;
            const u16* srcp = (plane == 0) ? (Ah + Abase) : (Bh + Bbase);
            const u16* gp = srcp + (size_t)row*512 + k0 + ((sg ^ (row & 7)) << 3);
            ldg_lds16(gp, smem + chunk*512);
        }
        __syncthreads();
        #pragma unroll
        for (int f = 0; f < 2; ++f) {
            bf8 av[4], b0[4];
            #pragma unroll
            for (int mf = 0; mf < 4; ++mf) {
                const int row = wm + mf*16 + lr;
                const int ch = (f*4 + lg) ^ (row & 7);
                av[mf] = *(const bf8*)&smem[row*64 + (ch << 3)];
            }
            #pragma unroll
            for (int nf = 0; nf < 4; ++nf) {
                const int row = wn + nf*16 + lr;
                const int ch = (f*4 + lg) ^ (row & 7);
                b0[nf] = *(const bf8*)&smem[8192 + row*64 + (ch << 3)];
            }
            #pragma unroll
            for (int mf = 0; mf < 4; ++mf)
                #pragma unroll
                for (int nf = 0; nf < 4; ++nf)
                    acc[mf][nf] = MFMA(av[mf], b0[nf], acc[mf][nf]);
        }
    }

    #pragma unroll
    for (int nf = 0; nf < 4; ++nf) {
        const int o = n0 + wn + nf*16 + lr;
        const float bs = bias[o];
        #pragma unroll
        for (int mf = 0; mf < 4; ++mf) {
            const int s = m0 + wm + mf*16 + lg*4;
            const size_t ob = ((size_t)b*1024 + s)*512 + o;
            float4 r;
            r.x = acc[mf][nf][0] + bs + bf2f(Ah[ob])         + bf2f(Al[ob]);
            r.y = acc[mf][nf][1] + bs + bf2f(Ah[ob + 512])   + bf2f(Al[ob + 512]);
            r.z = acc[mf][nf][2] + bs + bf2f(Ah[ob + 1024])  + bf2f(Al[ob + 1024]);
            r.w = acc[mf][nf][3] + bs + bf2f(Ah[ob + 1536])  + bf2f(Al[ob + 1536]);
            *(float4*)&out[((size_t)b*512 + o)*1024 + s] = r;
        }
    }
}

extern "C" void kernel_launch(void* const* d_in, const int* in_sizes, int n_in,
                              void* d_out, int out_size, void* d_ws, size_t ws_size,
                              hipStream_t stream) {
    const float* x      = (const float*)d_in[0];
    const float* gn_w   = (const float*)d_in[1];
    const float* gn_b   = (const float*)d_in[2];
    const float* qkv_w  = (const float*)d_in[3];
    const float* qkv_b  = (const float*)d_in[4];
    const float* proj_w = (const float*)d_in[5];
    const float* proj_b = (const float*)d_in[6];
    float* out = (float*)d_out;

    u16* w = (u16*)d_ws;
    const size_t P = 8388608UL;           // B*C*S elements
    u16* xh = w;                                   // plane 0: xn_t hi; later oh
    u16* ol = w + P;                               // plane 1: attn lo output
    u16* qh = w + 2*P;                             // plane 2: q bf16
    u16* pwh = w + 3*P;                            // plane 3: proj_w bf16
    u16* kh = w + 4*P;                             // plane 4: k bf16
    u16* vh = w + 6*P;                             // plane 6: v bf16
    u16* oh = xh;
    // qkv_w cast -> d_out scratch (qkv_mfma only READS d_out; safe).
    u16* qwh = (u16*)d_out;
    // GN partials in plane 5 (always free)
    float2* partial = (float2*)(w + 5*P);          // 1024 float2

    hipLaunchKernelGGL(gn_partial_prep, dim3(5120), dim3(256), 0, stream,
                       x, partial, qkv_w, proj_w, qwh, pwh);
    hipLaunchKernelGGL(gn_apply, dim3(1024), dim3(256), 0, stream,
                       x, gn_w, gn_b, partial, xh);
    hipLaunchKernelGGL(qkv_mfma, dim3(8, 12, 16), dim3(256), 0, stream,
                       xh, qwh, qkv_b, qh, kh, vh);
    hipLaunchKernelGGL(attn_mfma, dim3(8, 128), dim3(256), 0, stream,
                       qh, kh, vh, oh, ol);
    hipLaunchKernelGGL(proj_mfma, dim3(8, 4, 16), dim3(256), 0, stream,
                       oh, ol, pwh, proj_b, out);
}

// Round 22
// 125.440 us; speedup vs baseline: 1.0560x; 1.0224x over previous
//
#include <hip/hip_runtime.h>
#include <math.h>

typedef unsigned short u16;
typedef __attribute__((ext_vector_type(8))) short bf8;
typedef __attribute__((ext_vector_type(4))) short s4v;
typedef __attribute__((ext_vector_type(4))) float f4;

#define MFMA(a, b, c) __builtin_amdgcn_mfma_f32_16x16x32_bf16(a, b, c, 0, 0, 0)

#if defined(__has_builtin)
#if __has_builtin(__builtin_amdgcn_exp2f)
#define EXP2(x) __builtin_amdgcn_exp2f(x)
#endif
#endif
#ifndef EXP2
#define EXP2(x) exp2f(x)
#endif

__device__ __forceinline__ u16 f2bf(float f) {
    unsigned u = __float_as_uint(f);
    u += 0x7fffu + ((u >> 16) & 1u);
    return (u16)(u >> 16);
}
__device__ __forceinline__ float bf2f(u16 h) {
    return __uint_as_float(((unsigned)h) << 16);
}
__device__ __forceinline__ void split2(float v, u16& h, u16& l) {
    h = f2bf(v);
    l = f2bf(v - bf2f(h));
}
__device__ __forceinline__ void ldg_lds16(const u16* g, u16* l) {
    __builtin_amdgcn_global_load_lds(
        (const __attribute__((address_space(1))) unsigned int*)g,
        (__attribute__((address_space(3))) unsigned int*)l, 16, 0, 0);
}

// ---------------------------------------------------------------------------
// Fused GN pass 1 + weight prep. Blocks [0,1024): x partial sums.
// Blocks [1024,5120): cast qkv_w (786432) then proj_w (262144) to bf16.
// ---------------------------------------------------------------------------
__global__ __launch_bounds__(256) void gn_partial_prep(
    const float* __restrict__ x, float2* __restrict__ partial,
    const float* __restrict__ wq, const float* __restrict__ wp,
    u16* __restrict__ qwh, u16* __restrict__ pwh)
{
    const int tid = threadIdx.x;
    if (blockIdx.x >= 1024) {
        const int i = (blockIdx.x - 1024) * 256 + tid;
        if (i < 786432) qwh[i] = f2bf(wq[i]);
        else            pwh[i - 786432] = f2bf(wp[i - 786432]);
        return;
    }
    const int p = blockIdx.x;
    const float4* x4 = (const float4*)x + (size_t)p * 2048;
    float s = 0.f, ss = 0.f;
    for (int i = tid; i < 2048; i += 256) {
        float4 v = x4[i];
        s  += v.x + v.y + v.z + v.w;
        ss += v.x*v.x + v.y*v.y + v.z*v.z + v.w*v.w;
    }
    for (int off = 32; off > 0; off >>= 1) {
        s  += __shfl_down(s, off);
        ss += __shfl_down(ss, off);
    }
    __shared__ float red[8];
    const int wvi = tid >> 6;
    if ((tid & 63) == 0) { red[wvi] = s; red[4 + wvi] = ss; }
    __syncthreads();
    if (tid == 0)
        partial[p] = make_float2(red[0] + red[1] + red[2] + red[3],
                                 red[4] + red[5] + red[6] + red[7]);
}

// ---------------------------------------------------------------------------
// GN pass 2: reduce own group's 8 partials (redundant per block, trivial),
// then normalize + bf16 + transpose to xn_t[b][s][c].
// ---------------------------------------------------------------------------
__global__ __launch_bounds__(256) void gn_apply(
    const float* __restrict__ x, const float* __restrict__ gw,
    const float* __restrict__ gb, const float2* __restrict__ partial,
    u16* __restrict__ xh)
{
    const int blk = blockIdx.x;
    const int bg = blk >> 3, sc = (blk & 7) * 128;
    const int b = bg >> 3, g = bg & 7;
    const size_t base = (size_t)bg * 65536;
    float s = 0.f, ss = 0.f;
    #pragma unroll
    for (int i = 0; i < 8; ++i) {
        float2 pp = partial[bg*8 + i];
        s += pp.x; ss += pp.y;
    }
    const float mu = s * (1.f / 65536.f);
    const float rstd = rsqrtf(ss * (1.f / 65536.f) - mu * mu + 1e-5f);
    const int tid = threadIdx.x;

    __shared__ float tile[64][65];
    for (int s0 = sc; s0 < sc + 128; s0 += 64) {
        for (int idx = tid; idx < 1024; idx += 256) {
            const int c = idx >> 4, s4i = (idx & 15) * 4;
            const float w = gw[g*64 + c], bb = gb[g*64 + c];
            float4 v = *(const float4*)&x[base + (size_t)c*1024 + s0 + s4i];
            tile[s4i + 0][c] = (v.x - mu)*rstd*w + bb;
            tile[s4i + 1][c] = (v.y - mu)*rstd*w + bb;
            tile[s4i + 2][c] = (v.z - mu)*rstd*w + bb;
            tile[s4i + 3][c] = (v.w - mu)*rstd*w + bb;
        }
        __syncthreads();
        for (int idx = tid; idx < 1024; idx += 256) {
            const int srow = idx >> 4, c4 = (idx & 15) * 4;
            s4v hv;
            #pragma unroll
            for (int j = 0; j < 4; ++j)
                hv[j] = (short)f2bf(tile[srow][c4 + j]);
            const size_t o = ((size_t)b*1024 + s0 + srow)*512 + g*64 + c4;
            *(s4v*)&xh[o] = hv;
        }
        __syncthreads();
    }
}

// ---------------------------------------------------------------------------
// QKV GEMM: pure bf16, 1 MFMA (16x16x32). BM=BN=128, BK=64. LDS 32 KB.
// q (scaled 0.125*log2e), k: bf16 [bh][s][64]; v: bf16 [bh][64][s].
// ---------------------------------------------------------------------------
__global__ __launch_bounds__(256, 4) void qkv_mfma(
    const u16* __restrict__ Ah, const u16* __restrict__ Bh,
    const float* __restrict__ bias,
    u16* __restrict__ qh, u16* __restrict__ kh, u16* __restrict__ vh)
{
    __shared__ u16 smem[2*8192];          // [A:128x64][B:128x64]
    const int tid = threadIdx.x;
    const int wv = tid >> 6, ln = tid & 63;
    const int lr = ln & 15, lg = ln >> 4;
    const int m0 = blockIdx.x * 128;
    const int n0 = blockIdx.y * 128;
    const int b  = blockIdx.z;
    const size_t Abase = ((size_t)b*1024 + m0) * 512;
    const size_t Bbase = (size_t)n0 * 512;
    const int wm = (wv >> 1) * 64, wn = (wv & 1) * 64;
    const int srr = ln >> 3, sg = ln & 7;

    f4 acc[4][4] = {};

    for (int k0 = 0; k0 < 512; k0 += 64) {
        __syncthreads();
        #pragma unroll
        for (int it = 0; it < 8; ++it) {
            const int chunk = wv*8 + it;           // 32 x 1KB chunks
            const int plane = chunk >> 4;          // 0=A, 1=B
            const int row = ((chunk & 15) << 3) + srr;
            const u16* srcp = (plane == 0) ? (Ah + Abase) : (Bh + Bbase);
            const u16* gp = srcp + (size_t)row*512 + k0 + ((sg ^ (row & 7)) << 3);
            ldg_lds16(gp, smem + chunk*512);
        }
        __syncthreads();
        #pragma unroll
        for (int f = 0; f < 2; ++f) {
            bf8 av[4], b0[4];
            #pragma unroll
            for (int mf = 0; mf < 4; ++mf) {
                const int row = wm + mf*16 + lr;
                const int ch = (f*4 + lg) ^ (row & 7);
                av[mf] = *(const bf8*)&smem[row*64 + (ch << 3)];
            }
            #pragma unroll
            for (int nf = 0; nf < 4; ++nf) {
                const int row = wn + nf*16 + lr;
                const int ch = (f*4 + lg) ^ (row & 7);
                b0[nf] = *(const bf8*)&smem[8192 + row*64 + (ch << 3)];
            }
            #pragma unroll
            for (int mf = 0; mf < 4; ++mf)
                #pragma unroll
                for (int nf = 0; nf < 4; ++nf)
                    acc[mf][nf] = MFMA(av[mf], b0[nf], acc[mf][nf]);
        }
    }

    #pragma unroll
    for (int nf = 0; nf < 4; ++nf) {
        const int o = n0 + wn + nf*16 + lr;
        const int which = o >> 9;
        const int hd = (o >> 6) & 7;
        const int dd = o & 63;
        const float bs = bias[o];
        const int bh = b*8 + hd;
        #pragma unroll
        for (int mf = 0; mf < 4; ++mf) {
            const int s = m0 + wm + mf*16 + lg*4;
            if (which == 2) {
                s4v hv;
                #pragma unroll
                for (int r = 0; r < 4; ++r)
                    hv[r] = (short)f2bf(acc[mf][nf][r] + bs);
                const size_t a = ((size_t)bh*64 + dd)*1024 + s;
                *(s4v*)&vh[a] = hv;
            } else {
                // q scaled by 1/sqrt(64)*log2(e): softmax in exp2 domain
                const float sc = (which == 0) ? 0.18033688011112042f : 1.f;
                u16* dst = (which == 0) ? qh : kh;
                const size_t a = ((size_t)bh*1024 + s)*64 + dd;
                #pragma unroll
                for (int r = 0; r < 4; ++r)
                    dst[a + (size_t)r*64] = f2bf((acc[mf][nf][r] + bs)*sc);
            }
        }
    }
}

// ---------------------------------------------------------------------------
// Flash attention, 2-phase pipelined, 3-phase tile body. QBLK=128 (wave owns
// 32 q-rows), KBLK=64. K and V double-buffered in LDS via global_load_lds;
// per tile: explicit vmcnt(0) drain + one barrier -> issue next-tile staging
// -> compute. Tile body grouped over both ii:
//   (1) S-phase: each kv LDS read feeds BOTH ii (halves Kt reads; 16
//       back-to-back MFMAs), (2) softmax both ii (one VALU burst, 2
//       independent chains), (3) PV-phase: each vv read feeds both ii
//       (halves Vt reads; Pt write->read distance spans whole softmax).
// S = K*Q; no max tracking (scores bounded); PV = P*V. Pt per-ii.
// No setprio (measured -10%). LDS 50 KB -> 3 blocks/CU.
// ---------------------------------------------------------------------------
__global__ __launch_bounds__(256, 3) void attn_mfma(
    const u16* __restrict__ qh_, const u16* __restrict__ kh_,
    const u16* __restrict__ vh_,
    u16* __restrict__ oh_, u16* __restrict__ ol_)
{
    __shared__ u16 Kt[2][64][64];
    __shared__ u16 Vt[2][64][64];
    __shared__ u16 Pt[4][2][16][72];      // [wave][ii][i][j(+pad)]
    const int tid = threadIdx.x;
    const int wv = tid >> 6, ln = tid & 63;
    const int lr = ln & 15, lg = ln >> 4;
    // XCD-aware swizzle: all 8 q-tiles of one bh on one XCD, consecutive.
    const int flat = blockIdx.x + (blockIdx.y << 3);
    const int bh = ((flat & 7) << 4) + (flat >> 6);
    const int q0 = ((flat >> 3) & 7) * 128;
    const size_t qkb = (size_t)bh * 65536;
    const int srr = ln >> 3, sg = ln & 7;

    bf8 qf[2][2];                         // [ii][f]
    #pragma unroll
    for (int ii = 0; ii < 2; ++ii)
        #pragma unroll
        for (int f = 0; f < 2; ++f)
            qf[ii][f] = *(const bf8*)&qh_[qkb
                + (size_t)(q0 + wv*32 + ii*16 + lr)*64 + f*32 + lg*8];

    float lpart[2] = {0.f, 0.f};
    f4 oacc[2][4] = {};

    // prologue: stage tile 0 into buf 0 (16 x 1KB chunks: K 0-7, V 8-15)
    #pragma unroll
    for (int it = 0; it < 4; ++it) {
        const int chunk = wv*4 + it;
        const int row = (chunk & 7)*8 + srr;
        const u16* gp = (chunk < 8)
            ? kh_ + qkb + (size_t)row*64 + ((sg ^ (row & 7)) << 3)
            : vh_ + qkb + (size_t)row*1024 + ((sg ^ (row & 7)) << 3);
        u16* dst = ((chunk < 8) ? &Kt[0][0][0] : &Vt[0][0][0]) + (chunk & 7)*512;
        ldg_lds16(gp, dst);
    }

    for (int t = 0; t < 16; ++t) {
        const int cur = t & 1;
        const int j0 = t * 64;
        const u16* kbuf = &Kt[cur][0][0];
        const u16* vbuf = &Vt[cur][0][0];

        // Explicit drain of this wave's outstanding global_load_lds, then
        // barrier: guarantees tile t is fully in LDS for every wave.
        asm volatile("s_waitcnt vmcnt(0)" ::: "memory");
        __syncthreads();

        // prefetch tile t+1 into the other buffer (in flight across compute)
        if (t < 15) {
            #pragma unroll
            for (int it = 0; it < 4; ++it) {
                const int chunk = wv*4 + it;
                const int row = (chunk & 7)*8 + srr;
                const u16* gp = (chunk < 8)
                    ? kh_ + qkb + (size_t)(j0 + 64 + row)*64
                          + ((sg ^ (row & 7)) << 3)
                    : vh_ + qkb + (size_t)row*1024 + j0 + 64
                          + ((sg ^ (row & 7)) << 3);
                u16* dst = ((chunk < 8) ? &Kt[cur^1][0][0] : &Vt[cur^1][0][0])
                           + (chunk & 7)*512;
                ldg_lds16(gp, dst);
            }
        }

        // --- phase 1: S for BOTH ii (shared kv reads, grouped MFMAs) ---
        f4 sacc[2][4] = {};
        #pragma unroll
        for (int jf = 0; jf < 4; ++jf)
            #pragma unroll
            for (int f = 0; f < 2; ++f) {
                const int row = jf*16 + lr;
                const int ch = (f*4 + lg) ^ (row & 7);
                const bf8 kv = *(const bf8*)&kbuf[row*64 + (ch << 3)];
                sacc[0][jf] = MFMA(kv, qf[0][f], sacc[0][jf]);
                sacc[1][jf] = MFMA(kv, qf[1][f], sacc[1][jf]);
            }

        // --- phase 2: softmax for BOTH ii (one VALU burst) ---
        #pragma unroll
        for (int ii = 0; ii < 2; ++ii) {
            float ps = 0.f;
            #pragma unroll
            for (int jf = 0; jf < 4; ++jf) {
                s4v hv;
                #pragma unroll
                for (int r = 0; r < 4; ++r) {
                    const float p = EXP2(sacc[ii][jf][r]);
                    ps += p;
                    hv[r] = (short)(__float_as_uint(p) >> 16);
                }
                *(s4v*)&Pt[wv][ii][lr][(jf*4 + lg)*4] = hv;
            }
            lpart[ii] += ps;
        }

        // --- phase 3: PV for BOTH ii (shared vv reads, grouped MFMAs) ---
        #pragma unroll
        for (int f = 0; f < 2; ++f) {
            const bf8 pa0 = *(const bf8*)&Pt[wv][0][lr][(f*4 + lg)*8];
            const bf8 pa1 = *(const bf8*)&Pt[wv][1][lr][(f*4 + lg)*8];
            #pragma unroll
            for (int nf = 0; nf < 4; ++nf) {
                const int row = nf*16 + lr;
                const int ch = (f*4 + lg) ^ (row & 7);
                const bf8 vv = *(const bf8*)&vbuf[row*64 + (ch << 3)];
                oacc[0][nf] = MFMA(pa0, vv, oacc[0][nf]);
                oacc[1][nf] = MFMA(pa1, vv, oacc[1][nf]);
            }
        }
    }

    #pragma unroll
    for (int ii = 0; ii < 2; ++ii) {
        lpart[ii] += __shfl_xor(lpart[ii], 16);
        lpart[ii] += __shfl_xor(lpart[ii], 32);
    }

    const int b = bh >> 3, h = bh & 7;
    #pragma unroll
    for (int ii = 0; ii < 2; ++ii) {
        float inv[4];
        #pragma unroll
        for (int r = 0; r < 4; ++r)
            inv[r] = 1.f / __shfl(lpart[ii], lg*4 + r);
        #pragma unroll
        for (int nf = 0; nf < 4; ++nf) {
            const int dd = nf*16 + lr;
            #pragma unroll
            for (int r = 0; r < 4; ++r) {
                const int s = q0 + wv*32 + ii*16 + lg*4 + r;
                const float val = oacc[ii][nf][r] * inv[r];
                const size_t a = ((size_t)b*1024 + s)*512 + h*64 + dd;
                u16 hh, ll; split2(val, hh, ll);
                oh_[a] = hh;
                ol_[a] = ll;
            }
        }
    }
}

// ---------------------------------------------------------------------------
// Proj GEMM + bias + residual. Pure bf16 GEMM (O_hi x W_hi, 1 MFMA);
// residual uses full O (hi+lo). LDS 32 KB.
// ---------------------------------------------------------------------------
__global__ __launch_bounds__(256, 4) void proj_mfma(
    const u16* __restrict__ Ah, const u16* __restrict__ Al,
    const u16* __restrict__ Bh,
    const float* __restrict__ bias, float* __restrict__ out)
{
    __shared__ u16 smem[2*8192];          // [A:128x64][B:128x64]
    const int tid = threadIdx.x;
    const int wv = tid >> 6, ln = tid & 63;
    const int lr = ln & 15, lg = ln >> 4;
    const int m0 = blockIdx.x * 128;
    const int n0 = blockIdx.y * 128;
    const int b  = blockIdx.z;
    const size_t Abase = ((size_t)b*1024 + m0) * 512;
    const size_t Bbase = (size_t)n0 * 512;
    const int wm = (wv >> 1) * 64, wn = (wv & 1) * 64;
    const int srr = ln >> 3, sg = ln & 7;

    f4 acc[4][4] = {};

    for (int k0 = 0; k0 < 512; k0 += 64) {
        __syncthreads();
        #pragma unroll
        for (int it = 0; it < 8; ++it) {
            const int chunk = wv*8 + it;
            const int plane = chunk >> 4;          // 0=A, 1=B
            const int row = ((chunk & 15) << 3) + srr;
            const u16* srcp = (plane == 0) ? (Ah + Abase) : (Bh + Bbase);
            const u16* gp = srcp + (size_t)row*512 + k0 + ((sg ^ (row & 7)) << 3);
            ldg_lds16(gp, smem + chunk*512);
        }
        __syncthreads();
        #pragma unroll
        for (int f = 0; f < 2; ++f) {
            bf8 av[4], b0[4];
            #pragma unroll
            for (int mf = 0; mf < 4; ++mf) {
                const int row = wm + mf*16 + lr;
                const int ch = (f*4 + lg) ^ (row & 7);
                av[mf] = *(const bf8*)&smem[row*64 + (ch << 3)];
            }
            #pragma unroll
            for (int nf = 0; nf < 4; ++nf) {
                const int row = wn + nf*16 + lr;
                const int ch = (f*4 + lg) ^ (row & 7);
                b0[nf] = *(const bf8*)&smem[8192 + row*64 + (ch << 3)];
            }
            #pragma unroll
            for (int mf = 0; mf < 4; ++mf)
                #pragma unroll
                for (int nf = 0; nf < 4; ++nf)
                    acc[mf][nf] = MFMA(av[mf], b0[nf], acc[mf][nf]);
        }
    }

    #pragma unroll
    for (int nf = 0; nf < 4; ++nf) {
        const int o = n0 + wn + nf*16 + lr;
        const float bs = bias[o];
        #pragma unroll
        for (int mf = 0; mf < 4; ++mf) {
            const int s = m0 + wm + mf*16 + lg*4;
            const size_t ob = ((size_t)b*1024 + s)*512 + o;
            float4 r;
            r.x = acc[mf][nf][0] + bs + bf2f(Ah[ob])         + bf2f(Al[ob]);
            r.y = acc[mf][nf][1] + bs + bf2f(Ah[ob + 512])   + bf2f(Al[ob + 512]);
            r.z = acc[mf][nf][2] + bs + bf2f(Ah[ob + 1024])  + bf2f(Al[ob + 1024]);
            r.w = acc[mf][nf][3] + bs + bf2f(Ah[ob + 1536])  + bf2f(Al[ob + 1536]);
            *(float4*)&out[((size_t)b*512 + o)*1024 + s] = r;
        }
    }
}

extern "C" void kernel_launch(void* const* d_in, const int* in_sizes, int n_in,
                              void* d_out, int out_size, void* d_ws, size_t ws_size,
                              hipStream_t stream) {
    const float* x      = (const float*)d_in[0];
    const float* gn_w   = (const float*)d_in[1];
    const float* gn_b   = (const float*)d_in[2];
    const float* qkv_w  = (const float*)d_in[3];
    const float* qkv_b  = (const float*)d_in[4];
    const float* proj_w = (const float*)d_in[5];
    const float* proj_b = (const float*)d_in[6];
    float* out = (float*)d_out;

    u16* w = (u16*)d_ws;
    const size_t P = 8388608UL;           // B*C*S elements
    u16* xh = w;                                   // plane 0: xn_t hi; later oh
    u16* ol = w + P;                               // plane 1: attn lo output
    u16* qh = w + 2*P;                             // plane 2: q bf16
    u16* pwh = w + 3*P;                            // plane 3: proj_w bf16
    u16* kh = w + 4*P;                             // plane 4: k bf16
    u16* vh = w + 6*P;                             // plane 6: v bf16
    u16* oh = xh;
    // qkv_w cast -> d_out scratch (qkv_mfma only READS d_out; safe).
    u16* qwh = (u16*)d_out;
    // GN partials in plane 5 (always free)
    float2* partial = (float2*)(w + 5*P);          // 1024 float2

    hipLaunchKernelGGL(gn_partial_prep, dim3(5120), dim3(256), 0, stream,
                       x, partial, qkv_w, proj_w, qwh, pwh);
    hipLaunchKernelGGL(gn_apply, dim3(1024), dim3(256), 0, stream,
                       x, gn_w, gn_b, partial, xh);
    hipLaunchKernelGGL(qkv_mfma, dim3(8, 12, 16), dim3(256), 0, stream,
                       xh, qwh, qkv_b, qh, kh, vh);
    hipLaunchKernelGGL(attn_mfma, dim3(8, 128), dim3(256), 0, stream,
                       qh, kh, vh, oh, ol);
    hipLaunchKernelGGL(proj_mfma, dim3(8, 4, 16), dim3(256), 0, stream,
                       oh, ol, pwh, proj_b, out);
}